// Round 12
// baseline (390.870 us; speedup 1.0000x reference)
//
#include <hip/hip_runtime.h>

// Problem constants (B, LQ, LK, D from the reference)
#define B_  8
#define LQ_ 2048
#define LK_ 2048
#define D_  1024

typedef unsigned short u16;
using short8  = __attribute__((ext_vector_type(8))) short;   // 8 bf16 = 4 VGPRs (MFMA A/B frag)
using floatx4 = __attribute__((ext_vector_type(4))) float;   // MFMA C/D frag

#define GAS __attribute__((address_space(1)))
#define LAS __attribute__((address_space(3)))

__device__ __forceinline__ u16 f2bf(float f) {
  unsigned u = __float_as_uint(f);
  u += 0x7fffu + ((u >> 16) & 1u);   // round-to-nearest-even
  return (u16)(u >> 16);
}
__device__ __forceinline__ float bf2f(u16 h) {
  return __uint_as_float(((unsigned)h) << 16);
}

// ---------------------------------------------------------------------------
// prep (unchanged)
// ---------------------------------------------------------------------------
__global__ void prep(const float* __restrict__ in, const float* __restrict__ mem,
                     const float* __restrict__ ds, u16* __restrict__ qb,
                     u16* __restrict__ mb, u16* __restrict__ mbT,
                     float* __restrict__ denom) {
  __shared__ u16 tile[64][68];
  int tid = threadIdx.x;
  int tx = tid & 15, ty = tid >> 4;
  int b = blockIdx.z;

  if (denom && blockIdx.y == 16 && blockIdx.x == 0 && blockIdx.z == 0) {
    float4 z = {0.f, 0.f, 0.f, 0.f};
    float4* d4 = (float4*)denom;
#pragma unroll
    for (int i = 0; i < (B_ * LQ_ / 4) / 256; i++)
      d4[tid + i * 256] = z;
  }

  if (blockIdx.y < 16) {
    int k0 = blockIdx.x * 64, d0 = blockIdx.y * 64;
    const float* mB = mem + (size_t)b * LK_ * D_;
    u16* mbB = mb  + (size_t)b * LK_ * D_;
    u16* mtB = mbT + (size_t)b * D_ * LK_;
#pragma unroll
    for (int i = 0; i < 4; i++) {
      int r = ty + 16 * i;
      float4 v = *(const float4*)(mB + (size_t)(k0 + r) * D_ + d0 + tx * 4);
      ushort4 h;
      h.x = f2bf(v.x); h.y = f2bf(v.y); h.z = f2bf(v.z); h.w = f2bf(v.w);
      *(ushort4*)(mbB + (size_t)(k0 + r) * D_ + d0 + tx * 4) = h;
      *(ushort4*)(&tile[r][tx * 4]) = h;
    }
    __syncthreads();
#pragma unroll
    for (int i = 0; i < 4; i++) {
      int rr = ty + 16 * i;
      ushort4 o;
      o.x = tile[tx * 4 + 0][rr];
      o.y = tile[tx * 4 + 1][rr];
      o.z = tile[tx * 4 + 2][rr];
      o.w = tile[tx * 4 + 3][rr];
      *(ushort4*)(mtB + (size_t)(d0 + rr) * LK_ + k0 + tx * 4) = o;
    }
  } else {
    int q0 = blockIdx.x * 64, d0 = (blockIdx.y - 16) * 64;
    const float* iB = in + (size_t)b * LQ_ * D_;
    u16* qB = qb + (size_t)b * LQ_ * D_;
    float4 s4 = *(const float4*)(ds + d0 + tx * 4);
#pragma unroll
    for (int i = 0; i < 4; i++) {
      int r = ty + 16 * i;
      float4 v = *(const float4*)(iB + (size_t)(q0 + r) * D_ + d0 + tx * 4);
      ushort4 h;
      h.x = f2bf(v.x * s4.x); h.y = f2bf(v.y * s4.y);
      h.z = f2bf(v.z * s4.z); h.w = f2bf(v.w * s4.w);
      *(ushort4*)(qB + (size_t)(q0 + r) * D_ + d0 + tx * 4) = h;
    }
  }
}

// ---------------------------------------------------------------------------
// gemm_bt: C[M,N] = A[M,K] * B[N,K]^T per batch.
// v11: B DIRECT-TO-REGISTER with ZERO-DRAIN SYNC ONLY (round-11 decision).
//   v9/v10 (counted-vmcnt ledger) failed with IDENTICAL absmax across two
//   binaries -> not a compile-order race; either a vmcnt-retirement
//   semantic I mis-modeled or an addressing bug. v11 removes ALL counted
//   waits: only lgkmcnt(0) / vmcnt(0) / one barrier per tile — the exact
//   sync pattern that passed rounds 5/7b/8. This cleanly tests the
//   round-9 theory (LDS traffic 256 KiB/tile is co-critical with MFMA;
//   removing B from LDS drops it to 160 KiB ~1550 cy < 2483 cy MFMA):
//   PASS -> theory measured; FAIL 0.188 -> B-gather addressing is wrong,
//   abandon B-direct next round.
// Geometry: 256x256 tile, BK=64, 8 waves (2M x 4N), wave tile 128x64,
//   acc[8][4] (128 AGPR). LDS = A only, [2 buf][256 r][64 k] = 64 KiB.
//   A swizzle (proven 0-conflict): 16B chunk (row, sl) holds global k-chunk
//   sl^(row&7); global SOURCE pre-swizzled, LDS dest linear, ds_read addr
//   swizzled (rule 21).
// B gather: lane's frag = B[tn*256 + wn + n*16 + lm][kt + ks*32 + quad*8
//   .. +7] — quad-contiguous 64B row slices, 64B-aligned, L2-hot panel.
//   Identical logical content to the LDS path of rounds 1-8.
// Schedule per tile (all drains, no counts):
//   top:   stage A(t+1) -> nb (4 vm; lands under the whole tile)
//   RD af(k0) 8 ds; LG0; 32 MFMA (af x bf[0..3])
//   GATH bf[0..3] <- (t+1,k0)   (last use was the k0 cluster; lands
//                                under the k1 cluster)
//   RD af(k1) 8 ds; LG0; 32 MFMA (af x bf[4..7])
//   GATH bf[4..7] <- (t+1,k1)
//   VM0 (stage + both gathers resident; only the k1 gather is young,
//        ~300cy stall ~ 10% of tile — price of order-insensitivity)
//   s_barrier
// WAR safety: every bank overwrite (af re-read, bf refill) is issued
//   AFTER the MFMA cluster that last reads it; load writebacks land
//   >=200cy after issue while MFMA source reads complete within ~8cy of
//   issue -> safe (round-5 precedent).
// Frag banks: af[8]+bf[8] = 16 short8 = 64 VGPR (proven spill-free).
// MODE 1: score GEMM; E=exp(s) bf16 (masked->0) + atomic denom row sums.
// MODE 0: out GEMM; divides by denom[row], stores f32.
// MODE 2: fallback (in-loop rowsum from af at each k-half).
// ---------------------------------------------------------------------------
template <int MODE>
__global__ __launch_bounds__(512, 2) void gemm_bt(
    const u16* __restrict__ A, const u16* __restrict__ Bm,
    void* __restrict__ C, const float* __restrict__ mask,
    float* __restrict__ denom, int K, int ld, int ldc,
    size_t sA, size_t sB, size_t sC) {
  __shared__ __align__(16) u16 As[2 * 16384];   // [buf][256 rows][64 k] u16

  const int tid = threadIdx.x;
  const int lane = tid & 63, w = tid >> 6;
  const int lm = lane & 15, quad = (lane >> 4) & 3;
  const int wm = (w >> 2) * 128, wn = (w & 3) * 64;

  // ---- swizzle: batch = bid&7 (XCD affinity), GM=4 m-groups, n-fast ----
  const int tiles_n = gridDim.x;
  int bid = (blockIdx.z * gridDim.y + blockIdx.y) * tiles_n + blockIdx.x;
  int bz = bid & 7;
  int s = bid >> 3;
  const int GM = 4;
  int per_group = GM * tiles_n;
  int group = s / per_group;
  int rem = s - group * per_group;
  int tm = group * GM + (rem & (GM - 1));
  int tn = rem >> 2;

  const u16* Ab = A  + (size_t)bz * sA + (size_t)(tm * 256) * ld;
  const u16* Bb = Bm + (size_t)bz * sB + (size_t)(tn * 256) * ld;

  // ---- A staging: 2048 16B-chunks per tile, 4/thread. rho=c>>3 (row),
  // sl=c&7 (slot). LDS dest linear (chunk c at byte c*16); global source
  // pre-swizzled: k-chunk = sl ^ (rho&7).
  int goff[4];
#pragma unroll
  for (int j = 0; j < 4; j++) {
    int c = tid + 512 * j;
    int rho = c >> 3, sl = c & 7;
    goff[j] = rho * ld + (sl ^ (rho & 7)) * 8;   // elements
  }

  auto stageA = [&](int buf, int k0) {
#pragma unroll
    for (int j = 0; j < 4; j++)
      __builtin_amdgcn_global_load_lds(
          (GAS void*)(Ab + goff[j] + k0),
          (LAS void*)(As + buf * 16384 + (tid + 512 * j) * 8), 16, 0, 0);
  };

  // ---- A fragment reads: logical k-chunk (ks*4+quad) at row (base16+lm),
  // swizzled slot = chunk ^ (lm&7)  (row&7 == lm&7).
  const int ka0 = ((0 + quad) ^ (lm & 7)) * 8;
  const int ka1 = ((4 + quad) ^ (lm & 7)) * 8;

  // ---- B direct-gather base: lane's row offset (constant across tiles)
  const u16* Bl = Bb + (size_t)(wn + lm) * ld + quad * 8;

  short8 af[8], bf[8];   // 16 short8 = 64 VGPR (spill-free footprint)
  floatx4 acc[8][4];
#pragma unroll
  for (int i = 0; i < 8; i++)
#pragma unroll
    for (int j = 0; j < 4; j++)
      acc[i][j] = {0.f, 0.f, 0.f, 0.f};
  float rs[8] = {0.f, 0.f, 0.f, 0.f, 0.f, 0.f, 0.f, 0.f};   // MODE 2 only

#define SB __builtin_amdgcn_sched_barrier(0)
#define LG0 { asm volatile("s_waitcnt lgkmcnt(0)" ::: "memory"); SB; }
#define VM0 { asm volatile("s_waitcnt vmcnt(0)" ::: "memory"); SB; }

  // gather one bf half: frags bf[KS*4+n] = B rows wn+n*16+lm, k-slice KS
#define GATH_H(KS, KT)                                                        \
  { _Pragma("unroll")                                                         \
    for (int n = 0; n < 4; n++)                                               \
      bf[(KS) * 4 + n] =                                                      \
          *(const short8*)(Bl + (size_t)n * 16 * ld + (KT) + (KS) * 32); }
  // read all 8 A m-frags at swizzled k-offset KAX from buffer CO
#define RD_A8(KAX, CO)                                                        \
  { _Pragma("unroll")                                                         \
    for (int m = 0; m < 8; m++)                                               \
      af[m] = *(const short8*)(As + (CO) +                                    \
          ((wm + m * 16 + lm) << 6) + (KAX)); }
#define SUMS                                                                  \
  if constexpr (MODE == 2) {                                                  \
    _Pragma("unroll")                                                         \
    for (int m = 0; m < 8; m++) {                                             \
      uint4 u = *(const uint4*)&af[m];                                        \
      rs[m] +=                                                                \
          __uint_as_float(u.x << 16) + __uint_as_float(u.x & 0xffff0000u)     \
        + __uint_as_float(u.y << 16) + __uint_as_float(u.y & 0xffff0000u)     \
        + __uint_as_float(u.z << 16) + __uint_as_float(u.z & 0xffff0000u)     \
        + __uint_as_float(u.w << 16) + __uint_as_float(u.w & 0xffff0000u);    \
    } }
  // 32-MFMA cluster: all 8 m-frags x 4 n-frags of bf half HB
#define MMC_K(HB)                                                             \
  { __builtin_amdgcn_s_setprio(1);                                            \
    _Pragma("unroll")                                                         \
    for (int m = 0; m < 8; m++)                                               \
      _Pragma("unroll")                                                       \
      for (int n = 0; n < 4; n++)                                             \
        acc[m][n] = __builtin_amdgcn_mfma_f32_16x16x32_bf16(                  \
            af[m], bf[(HB) * 4 + n], acc[m][n], 0, 0, 0);                     \
    __builtin_amdgcn_s_setprio(0); }

  const int NT = K >> 6;
  // prologue: stage A(tile0); gather bf(tile0) both halves; drain; barrier.
  stageA(0, 0);
  SB;
  GATH_H(0, 0)
  GATH_H(1, 0)
  SB;
  VM0;
  __builtin_amdgcn_s_barrier();

  for (int t = 0; t < NT; ++t) {
    const int co = (t & 1) * 16384;
    const int nbuf = (t & 1) ^ 1;
    const bool have = (t + 1 < NT);
    const int kn = (t + 1) << 6;

    SB;
    if (have) stageA(nbuf, kn);
    SB;
    RD_A8(ka0, co)
    SB;
    LG0;
    SUMS
    MMC_K(0)                       // k0 cluster: af(k0) x bf[0..3]
    if (have) { GATH_H(0, kn) }    // refill k0 half (last use above)
    SB;
    RD_A8(ka1, co)
    SB;
    LG0;
    SUMS
    MMC_K(1)                       // k1 cluster: af(k1) x bf[4..7]
    if (have) { GATH_H(1, kn) }    // refill k1 half (last use above)
    SB;
    VM0;                           // stage + both gathers resident
    __builtin_amdgcn_s_barrier();
  }
#undef MMC_K
#undef SUMS
#undef RD_A8
#undef GATH_H
#undef LG0
#undef VM0
#undef SB

  // C/D layout: col = lane&15, row = quad*4 + reg  [measured m89/m91]
  const int gm0 = tm * 256 + wm + quad * 4;
  const int gn0 = tn * 256 + wn + lm;
  const size_t cb = (size_t)bz * sC;

  if constexpr (MODE == 1) {
    const float* mrow = mask + (size_t)bz * LK_;
    bool msk[4];
#pragma unroll
    for (int ni = 0; ni < 4; ni++) msk[ni] = (mrow[gn0 + ni * 16] != 0.0f);
#pragma unroll
    for (int mi = 0; mi < 8; mi++) {
#pragma unroll
      for (int r = 0; r < 4; r++) {
        int row = gm0 + mi * 16 + r;
        size_t rowoff = cb + (size_t)row * ldc + gn0;
        float part = 0.f;
#pragma unroll
        for (int ni = 0; ni < 4; ni++) {
          float e = msk[ni] ? 0.f : __expf(acc[mi][ni][r]);
          u16 h = f2bf(e);
          ((u16*)C)[rowoff + ni * 16] = h;
          part += bf2f(h);   // sum the rounded value GEMM2 will actually use
        }
        if (denom) {
          part += __shfl_xor(part, 1, 64);
          part += __shfl_xor(part, 2, 64);
          part += __shfl_xor(part, 4, 64);
          part += __shfl_xor(part, 8, 64);
          if (lm == 0) atomicAdd(&denom[(size_t)bz * LQ_ + row], part);
        }
      }
    }
  } else if constexpr (MODE == 0) {
#pragma unroll
    for (int mi = 0; mi < 8; mi++) {
#pragma unroll
      for (int r = 0; r < 4; r++) {
        int row = gm0 + mi * 16 + r;
        float is = 1.0f / denom[(size_t)bz * LQ_ + row];
        size_t rowoff = cb + (size_t)row * ldc + gn0;
#pragma unroll
        for (int ni = 0; ni < 4; ni++)
          ((float*)C)[rowoff + ni * 16] = acc[mi][ni][r] * is;
      }
    }
  } else {  // MODE 2 fallback: finish in-loop rowsum
    float inv[8];
#pragma unroll
    for (int mi = 0; mi < 8; mi++) {
      rs[mi] += __shfl_xor(rs[mi], 16, 64);
      rs[mi] += __shfl_xor(rs[mi], 32, 64);
      inv[mi] = 1.0f / rs[mi];
    }
#pragma unroll
    for (int mi = 0; mi < 8; mi++) {
#pragma unroll
      for (int r = 0; r < 4; r++) {
        size_t rowoff = cb + (size_t)(gm0 + mi * 16 + r) * ldc + gn0;
        float is = __shfl(inv[mi], quad * 4 + r, 64);
#pragma unroll
        for (int ni = 0; ni < 4; ni++)
          ((float*)C)[rowoff + ni * 16] = acc[mi][ni][r] * is;
      }
    }
  }
}

// ---------------------------------------------------------------------------
// kernel_launch
// Inputs: 0=input [B,LQ,D] f32, 1=memory [B,LK,D] f32, 2=mask [B,LK] f32,
//         3=w_input [1,D] f32 (UNUSED: softmax is shift-invariant along k),
//         4=dot_scale [D] f32.
// Workspace layout (160 MB + 64 KB):
//   qb bf16 [B,LQ,D] @0 | mb bf16 [B,LK,D] @32MB | mbT bf16 [B,D,LK] @64MB
//   E bf16 [B,LQ,LK] @96MB | denom f32 [B,LQ] @160MB (if ws permits)
// ---------------------------------------------------------------------------
extern "C" void kernel_launch(void* const* d_in, const int* in_sizes, int n_in,
                              void* d_out, int out_size, void* d_ws, size_t ws_size,
                              hipStream_t stream) {
  const float* input  = (const float*)d_in[0];
  const float* memory = (const float*)d_in[1];
  const float* mask   = (const float*)d_in[2];
  const float* dscale = (const float*)d_in[4];

  char* ws = (char*)d_ws;
  u16* qb  = (u16*)(ws);
  u16* mb  = (u16*)(ws + (size_t)32 * 1024 * 1024);
  u16* mbT = (u16*)(ws + (size_t)64 * 1024 * 1024);
  u16* E   = (u16*)(ws + (size_t)96 * 1024 * 1024);
  size_t base = (size_t)160 * 1024 * 1024;
  bool have_denom = ws_size >= base + (size_t)B_ * LQ_ * sizeof(float);
  float* denom = have_denom ? (float*)(ws + base) : nullptr;
  float* out = (float*)d_out;

  hipLaunchKernelGGL(prep, dim3(32, 32, B_), dim3(256), 0, stream,
                     input, memory, dscale, qb, mb, mbT, denom);
  // E = exp(qb * mb^T), masked -> 0 : M=LQ, N=LK, K=D (+ denom accumulation)
  hipLaunchKernelGGL((gemm_bt<1>), dim3(LK_ / 256, LQ_ / 256, B_), dim3(512), 0,
                     stream, qb, mb, (void*)E, mask, denom, D_, D_, LK_,
                     (size_t)LQ_ * D_, (size_t)LK_ * D_, (size_t)LQ_ * LK_);
  // out = (E * mbT^T) / denom : M=LQ, N=D, K=LK
  if (have_denom)
    hipLaunchKernelGGL((gemm_bt<0>), dim3(D_ / 256, LQ_ / 256, B_), dim3(512), 0,
                       stream, E, mbT, (void*)out, nullptr, denom, LK_, LK_, D_,
                       (size_t)LQ_ * LK_, (size_t)D_ * LK_, (size_t)LQ_ * D_);
  else
    hipLaunchKernelGGL((gemm_bt<2>), dim3(D_ / 256, LQ_ / 256, B_), dim3(512), 0,
                       stream, E, mbT, (void*)out, nullptr, nullptr, LK_, LK_, D_,
                       (size_t)LQ_ * LK_, (size_t)D_ * LK_, (size_t)LQ_ * D_);
}